// Round 1
// baseline (257.937 us; speedup 1.0000x reference)
//
#include <hip/hip_runtime.h>

typedef _Float16 half8 __attribute__((ext_vector_type(8)));
typedef _Float16 half2v __attribute__((ext_vector_type(2)));
typedef float float4v __attribute__((ext_vector_type(4)));

// ---- helpers ----
__device__ __forceinline__ float hmul_acc(unsigned a, unsigned b, float c) {
  half2v ha = __builtin_bit_cast(half2v, a);
  half2v hb = __builtin_bit_cast(half2v, b);
  c += (float)ha[0] * (float)hb[0];
  c += (float)ha[1] * (float)hb[1];
  return c;
}
__device__ __forceinline__ unsigned hscale(unsigned a, float s) {
  half2v ha = __builtin_bit_cast(half2v, a);
  half2v r;
  r[0] = (_Float16)((float)ha[0] * s);
  r[1] = (_Float16)((float)ha[1] * s);
  return __builtin_bit_cast(unsigned, r);
}

// ---- fp32 -> fp16 convert ----
__global__ void cvt_f2h(const float4* __restrict__ s, ushort4* __restrict__ d, int n4) {
  int i = blockIdx.x * 256 + threadIdx.x;
  if (i < n4) {
    float4 v = s[i];
    _Float16 a = (_Float16)v.x, b = (_Float16)v.y, c = (_Float16)v.z, e = (_Float16)v.w;
    ushort4 o;
    o.x = __builtin_bit_cast(unsigned short, a);
    o.y = __builtin_bit_cast(unsigned short, b);
    o.z = __builtin_bit_cast(unsigned short, c);
    o.w = __builtin_bit_cast(unsigned short, e);
    d[i] = o;
  }
}

// ---- GEMM1: qk = x16 @ wqk16^T, epilogue scatters to q16/k16 (b,h,t,yx,j) fp16 ----
// A: (65536,256) halfs row-major; B: (512,256) halfs row-major; K=256, tiles 128x128x32
__global__ __launch_bounds__(256, 2)
void gemm_qk(const _Float16* __restrict__ A, const _Float16* __restrict__ Bw,
             _Float16* __restrict__ qo, _Float16* __restrict__ ko) {
  __shared__ uint4 Ash[512];
  __shared__ uint4 Bsh[512];
  const int tid = threadIdx.x;
  const int lane = tid & 63, w = tid >> 6;
  const int wm = w >> 1, wn = w & 1;
  const int ml = lane & 15, qd = lane >> 4;
  const int m0 = blockIdx.y * 128, n0 = blockIdx.x * 128;

  float4v acc[4][4];
  float4v z = {0.f, 0.f, 0.f, 0.f};
#pragma unroll
  for (int i = 0; i < 4; ++i)
#pragma unroll
    for (int j = 0; j < 4; ++j) acc[i][j] = z;

  const _Float16* Ap = A + (size_t)m0 * 256;
  const _Float16* Bp = Bw + (size_t)n0 * 256;

  for (int kt = 0; kt < 8; ++kt) {
    int k0 = kt * 32;
#pragma unroll
    for (int i = 0; i < 2; ++i) {
      int g = tid + i * 256;
      int row = g >> 2, kb = g & 3;
      uint4 va = *(const uint4*)(Ap + row * 256 + k0 + kb * 8);
      uint4 vb = *(const uint4*)(Bp + row * 256 + k0 + kb * 8);
      int slot = (row << 2) | (kb ^ ((row >> 1) & 3));
      Ash[slot] = va;
      Bsh[slot] = vb;
    }
    __syncthreads();
    half8 af[4], bf[4];
#pragma unroll
    for (int im = 0; im < 4; ++im) {
      int rowA = wm * 64 + im * 16 + ml;
      int sA = (rowA << 2) | (qd ^ ((rowA >> 1) & 3));
      af[im] = *(const half8*)((const _Float16*)Ash + sA * 8);
      int rowB = wn * 64 + im * 16 + ml;
      int sB = (rowB << 2) | (qd ^ ((rowB >> 1) & 3));
      bf[im] = *(const half8*)((const _Float16*)Bsh + sB * 8);
    }
#pragma unroll
    for (int im = 0; im < 4; ++im)
#pragma unroll
      for (int in = 0; in < 4; ++in)
        acc[im][in] = __builtin_amdgcn_mfma_f32_16x16x32_f16(af[im], bf[in], acc[im][in], 0, 0, 0);
    __syncthreads();
  }

  // epilogue: C/D layout col=lane&15, row=quad*4+r
#pragma unroll
  for (int im = 0; im < 4; ++im) {
    int rowr0 = m0 + wm * 64 + im * 16 + qd * 4;
#pragma unroll
    for (int in = 0; in < 4; ++in) {
      int col = n0 + wn * 64 + in * 16 + ml;
      int s = col >> 8, h = (col >> 5) & 7, j = col & 31;
      _Float16* dst = s ? ko : qo;
#pragma unroll
      for (int r = 0; r < 4; ++r) {
        int rowr = rowr0 + r;
        int b = rowr >> 13, n = rowr & 8191;
        int t = n >> 10, yx = n & 1023;
        int p = b * 64 + h * 8 + t;
        dst[((size_t)p * 1024 + yx) * 32 + j] = (_Float16)acc[im][in][r];
      }
    }
  }
}

// ---- correlation + normalize + (corr @ w_corr^T + b_corr) fused ----
// grid: 512 volumes * 4 tiles of 16x16; block 256
__global__ __launch_bounds__(256, 2)
void corr_kernel(const _Float16* __restrict__ q16, const _Float16* __restrict__ k16,
                 const float* __restrict__ wcorr, const float* __restrict__ bcorr,
                 _Float16* __restrict__ outp) {
  __shared__ uint4 smem[2304];  // k-tile (1936 granules) then reused as corr matrix [256][72] halfs
  __shared__ uint4 wcs[288];    // w_corr fp16 [32][72]
  __shared__ float bcs[32];

  const int tid = threadIdx.x;
  const int bx = blockIdx.x;
  const int p = bx >> 2, tile = bx & 3;
  const int y0 = (tile >> 1) * 16, x0 = (tile & 1) * 16;
  const int b = p >> 6, h = (p >> 3) & 7, t = p & 7;
  const int pk = (t < 7) ? p + 1 : p;
  const int ty = tid >> 4, tx = tid & 15;

  // stage w_corr (fp16, k-padded to 72) and b_corr
  _Float16* wch = (_Float16*)wcs;
  for (int idx = tid; idx < 2304; idx += 256) {
    int d = idx / 72, kk = idx - d * 72;
    wch[idx] = (kk < 49) ? (_Float16)wcorr[d * 49 + kk] : (_Float16)0.f;
  }
  if (tid < 32) bcs[tid] = bcorr[tid];

  // stage k tile 22x22 vectors of 32 halfs (4 granules each), swizzled
  const _Float16* kbase = k16 + (size_t)pk * 32768;
#pragma unroll
  for (int i = 0; i < 8; ++i) {
    int g = tid + i * 256;
    if (g < 1936) {
      int vec = g >> 2, part = g & 3;
      int ky = vec / 22, kx = vec - ky * 22;
      int gy = y0 + ky - 3, gx = x0 + kx - 3;
      uint4 val = make_uint4(0u, 0u, 0u, 0u);
      if (gy >= 0 && gy < 32 && gx >= 0 && gx < 32)
        val = *(const uint4*)(kbase + ((size_t)gy * 32 + gx) * 32 + part * 8);
      int slot = (vec << 2) | (part ^ (vec & 3) ^ ((vec >> 2) & 3));
      smem[slot] = val;
    }
  }
  __syncthreads();

  // normalize k vectors in LDS (zero vectors stay zero: 1/max(0,eps)*0 == 0)
  for (int v = tid; v < 484; v += 256) {
    int base = v << 2;
    int sw = (v & 3) ^ ((v >> 2) & 3);
    uint4 gg[4];
#pragma unroll
    for (int pq = 0; pq < 4; ++pq) gg[pq] = smem[base | (pq ^ sw)];
    float ss = 0.f;
#pragma unroll
    for (int pq = 0; pq < 4; ++pq) {
      const unsigned* u = (const unsigned*)&gg[pq];
#pragma unroll
      for (int e = 0; e < 4; ++e) ss = hmul_acc(u[e], u[e], ss);
    }
    float sc = 1.f / fmaxf(sqrtf(ss), 1e-12f);
#pragma unroll
    for (int pq = 0; pq < 4; ++pq) {
      unsigned* u = (unsigned*)&gg[pq];
#pragma unroll
      for (int e = 0; e < 4; ++e) u[e] = hscale(u[e], sc);
      smem[base | (pq ^ sw)] = gg[pq];
    }
  }
  __syncthreads();

  // per-thread q vector (raw fp16) + its norm scale
  const _Float16* qptr = q16 + (size_t)p * 32768 + ((size_t)(y0 + ty) * 32 + (x0 + tx)) * 32;
  uint4 qv[4];
#pragma unroll
  for (int i = 0; i < 4; ++i) qv[i] = *(const uint4*)(qptr + i * 8);
  const unsigned* qu = (const unsigned*)qv;
  float qss = 0.f;
#pragma unroll
  for (int e = 0; e < 16; ++e) qss = hmul_acc(qu[e], qu[e], qss);
  float qsc = 1.f / fmaxf(sqrtf(qss), 1e-12f);

  // 49 correlations
  float corr[49];
#pragma unroll
  for (int dy = 0; dy < 7; ++dy) {
#pragma unroll
    for (int dx = 0; dx < 7; ++dx) {
      int vec = (ty + dy) * 22 + (tx + dx);
      int base = vec << 2;
      int sw = (vec & 3) ^ ((vec >> 2) & 3);
      float c = 0.f;
#pragma unroll
      for (int pq = 0; pq < 4; ++pq) {
        uint4 kk = smem[base | (pq ^ sw)];
        const unsigned* ku = (const unsigned*)&kk;
#pragma unroll
        for (int e = 0; e < 4; ++e) c = hmul_acc(qu[pq * 4 + e], ku[e], c);
      }
      corr[dy * 7 + dx] = c * qsc;
    }
  }
  __syncthreads();  // all k-tile reads done; smem reused as corr matrix

  // write corr row (pos = tid) as fp16, padded to 72
  _Float16* corrm = (_Float16*)smem;
#pragma unroll
  for (int i = 0; i < 9; ++i) {
    uint4 val;
    unsigned* vu = (unsigned*)&val;
#pragma unroll
    for (int e = 0; e < 4; ++e) {
      int idx = i * 8 + e * 2;
      half2v hh;
      hh[0] = (_Float16)(idx < 49 ? corr[idx] : 0.f);
      hh[1] = (_Float16)(idx + 1 < 49 ? corr[idx + 1] : 0.f);
      vu[e] = __builtin_bit_cast(unsigned, hh);
    }
    smem[tid * 9 + i] = val;
  }
  __syncthreads();

  // MFMA: (256 pos x 64k) @ (64k x 32d): wave w handles m-tiles 4w..4w+3, 2 n-tiles
  const int lane = tid & 63, w = tid >> 6;
  const int ml = lane & 15, qd = lane >> 4;
  float4v vacc[4][2];
  float4v z = {0.f, 0.f, 0.f, 0.f};
#pragma unroll
  for (int im = 0; im < 4; ++im) { vacc[im][0] = z; vacc[im][1] = z; }
#pragma unroll
  for (int ks = 0; ks < 2; ++ks) {
    half8 bfrag[2];
#pragma unroll
    for (int nt = 0; nt < 2; ++nt)
      bfrag[nt] = *(const half8*)(wch + (nt * 16 + ml) * 72 + ks * 32 + qd * 8);
#pragma unroll
    for (int im = 0; im < 4; ++im) {
      half8 afrag = *(const half8*)(corrm + (w * 64 + im * 16 + ml) * 72 + ks * 32 + qd * 8);
#pragma unroll
      for (int nt = 0; nt < 2; ++nt)
        vacc[im][nt] = __builtin_amdgcn_mfma_f32_16x16x32_f16(afrag, bfrag[nt], vacc[im][nt], 0, 0, 0);
    }
  }

  // epilogue: v -> outpre[b, n, h*32+d] fp16
#pragma unroll
  for (int im = 0; im < 4; ++im) {
#pragma unroll
    for (int nt = 0; nt < 2; ++nt) {
      int d = nt * 16 + ml;
      float bias = bcs[d];
#pragma unroll
      for (int r = 0; r < 4; ++r) {
        int pos = w * 64 + im * 16 + qd * 4 + r;
        int py = pos >> 4, px = pos & 15;
        int n = t * 1024 + (y0 + py) * 32 + (x0 + px);
        outp[(((size_t)b * 8192 + n) << 8) + h * 32 + d] = (_Float16)(vacc[im][nt][r] + bias);
      }
    }
  }
}

// ---- proj GEMM: out = op16 @ wproj16^T + b_proj (fp32 out) ----
__global__ __launch_bounds__(256, 2)
void gemm_proj(const _Float16* __restrict__ A, const _Float16* __restrict__ Bw,
               const float* __restrict__ bp, float* __restrict__ out) {
  __shared__ uint4 Ash[512];
  __shared__ uint4 Bsh[512];
  const int tid = threadIdx.x;
  const int lane = tid & 63, w = tid >> 6;
  const int wm = w >> 1, wn = w & 1;
  const int ml = lane & 15, qd = lane >> 4;
  const int m0 = blockIdx.y * 128, n0 = blockIdx.x * 128;

  float4v acc[4][4];
  float4v z = {0.f, 0.f, 0.f, 0.f};
#pragma unroll
  for (int i = 0; i < 4; ++i)
#pragma unroll
    for (int j = 0; j < 4; ++j) acc[i][j] = z;

  const _Float16* Ap = A + (size_t)m0 * 256;
  const _Float16* Bp = Bw + (size_t)n0 * 256;

  for (int kt = 0; kt < 8; ++kt) {
    int k0 = kt * 32;
#pragma unroll
    for (int i = 0; i < 2; ++i) {
      int g = tid + i * 256;
      int row = g >> 2, kb = g & 3;
      uint4 va = *(const uint4*)(Ap + row * 256 + k0 + kb * 8);
      uint4 vb = *(const uint4*)(Bp + row * 256 + k0 + kb * 8);
      int slot = (row << 2) | (kb ^ ((row >> 1) & 3));
      Ash[slot] = va;
      Bsh[slot] = vb;
    }
    __syncthreads();
    half8 af[4], bf[4];
#pragma unroll
    for (int im = 0; im < 4; ++im) {
      int rowA = wm * 64 + im * 16 + ml;
      int sA = (rowA << 2) | (qd ^ ((rowA >> 1) & 3));
      af[im] = *(const half8*)((const _Float16*)Ash + sA * 8);
      int rowB = wn * 64 + im * 16 + ml;
      int sB = (rowB << 2) | (qd ^ ((rowB >> 1) & 3));
      bf[im] = *(const half8*)((const _Float16*)Bsh + sB * 8);
    }
#pragma unroll
    for (int im = 0; im < 4; ++im)
#pragma unroll
      for (int in = 0; in < 4; ++in)
        acc[im][in] = __builtin_amdgcn_mfma_f32_16x16x32_f16(af[im], bf[in], acc[im][in], 0, 0, 0);
    __syncthreads();
  }

#pragma unroll
  for (int im = 0; im < 4; ++im) {
    int rowr0 = m0 + wm * 64 + im * 16 + qd * 4;
#pragma unroll
    for (int in = 0; in < 4; ++in) {
      int col = n0 + wn * 64 + in * 16 + ml;
      float bias = bp[col];
#pragma unroll
      for (int r = 0; r < 4; ++r)
        out[(size_t)(rowr0 + r) * 256 + col] = acc[im][in][r] + bias;
    }
  }
}

extern "C" void kernel_launch(void* const* d_in, const int* in_sizes, int n_in,
                              void* d_out, int out_size, void* d_ws, size_t ws_size,
                              hipStream_t stream) {
  const float* x      = (const float*)d_in[0];
  const float* w_qk   = (const float*)d_in[1];
  const float* w_corr = (const float*)d_in[2];
  const float* b_corr = (const float*)d_in[3];
  const float* w_proj = (const float*)d_in[4];
  const float* b_proj = (const float*)d_in[5];
  float* out = (float*)d_out;

  char* ws = (char*)d_ws;
  _Float16* x16   = (_Float16*)(ws);
  _Float16* q16   = (_Float16*)(ws + 33554432);
  _Float16* k16   = (_Float16*)(ws + 67108864);
  _Float16* op16  = (_Float16*)(ws + 100663296);
  _Float16* wqk16 = (_Float16*)(ws + 134217728);
  _Float16* wpj16 = (_Float16*)(ws + 134479872);

  cvt_f2h<<<16384, 256, 0, stream>>>((const float4*)x, (ushort4*)x16, 4194304);
  cvt_f2h<<<128, 256, 0, stream>>>((const float4*)w_qk, (ushort4*)wqk16, 32768);
  cvt_f2h<<<64, 256, 0, stream>>>((const float4*)w_proj, (ushort4*)wpj16, 16384);
  gemm_qk<<<dim3(4, 512), 256, 0, stream>>>(x16, wqk16, q16, k16);
  corr_kernel<<<2048, 256, 0, stream>>>(q16, k16, w_corr, b_corr, op16);
  gemm_proj<<<dim3(2, 512), 256, 0, stream>>>(op16, wpj16, b_proj, out);
}

// Round 2
// 234.976 us; speedup vs baseline: 1.0977x; 1.0977x over previous
//
#include <hip/hip_runtime.h>

typedef _Float16 half8 __attribute__((ext_vector_type(8)));
typedef _Float16 half2v __attribute__((ext_vector_type(2)));
typedef float float4v __attribute__((ext_vector_type(4)));

// ---- helpers ----
__device__ __forceinline__ float dot2acc(unsigned a, unsigned b, float c) {
#if __has_builtin(__builtin_amdgcn_fdot2)
  return __builtin_amdgcn_fdot2(__builtin_bit_cast(half2v, a), __builtin_bit_cast(half2v, b), c, false);
#else
  half2v ha = __builtin_bit_cast(half2v, a);
  half2v hb = __builtin_bit_cast(half2v, b);
  c += (float)ha[0] * (float)hb[0];
  c += (float)ha[1] * (float)hb[1];
  return c;
#endif
}
__device__ __forceinline__ unsigned hscale(unsigned a, float s) {
  half2v ha = __builtin_bit_cast(half2v, a);
  half2v r;
  r[0] = (_Float16)((float)ha[0] * s);
  r[1] = (_Float16)((float)ha[1] * s);
  return __builtin_bit_cast(unsigned, r);
}
__device__ __forceinline__ void gload_lds16(const void* g, void* l) {
  __builtin_amdgcn_global_load_lds((const __attribute__((address_space(1))) unsigned*)g,
                                   (__attribute__((address_space(3))) unsigned*)l, 16, 0, 0);
}

// ---- fp32 -> fp16 convert, all three tensors in one launch ----
__global__ void cvt_all(const float4* __restrict__ x, const float4* __restrict__ wqk,
                        const float4* __restrict__ wpj,
                        ushort4* __restrict__ x16, ushort4* __restrict__ wqk16,
                        ushort4* __restrict__ wpj16) {
  int b = blockIdx.x;
  const float4* s;
  ushort4* d;
  int i;
  if (b < 16384) { s = x; d = x16; i = b * 256 + threadIdx.x; }
  else if (b < 16512) { s = wqk; d = wqk16; i = (b - 16384) * 256 + threadIdx.x; }
  else { s = wpj; d = wpj16; i = (b - 16512) * 256 + threadIdx.x; }
  float4 v = s[i];
  _Float16 a = (_Float16)v.x, bb = (_Float16)v.y, c = (_Float16)v.z, e = (_Float16)v.w;
  ushort4 o;
  o.x = __builtin_bit_cast(unsigned short, a);
  o.y = __builtin_bit_cast(unsigned short, bb);
  o.z = __builtin_bit_cast(unsigned short, c);
  o.w = __builtin_bit_cast(unsigned short, e);
  d[i] = o;
}

// ---- GEMM1: qk = x16 @ wqk16^T, epilogue scatters to q16/k16 (b,h,t,yx,j) fp16 ----
// Linear LDS layout (granule g = row*4+kb at halfs g*8), staged via global_load_lds x16B.
__global__ __launch_bounds__(256, 2)
void gemm_qk(const _Float16* __restrict__ A, const _Float16* __restrict__ Bw,
             _Float16* __restrict__ qo, _Float16* __restrict__ ko) {
  __shared__ _Float16 Ash[4096];
  __shared__ _Float16 Bsh[4096];
  const int tid = threadIdx.x;
  const int lane = tid & 63, w = tid >> 6;
  const int wm = w >> 1, wn = w & 1;
  const int ml = lane & 15, qd = lane >> 4;
  const int m0 = blockIdx.y * 128, n0 = blockIdx.x * 128;

  float4v acc[4][4];
  float4v z = {0.f, 0.f, 0.f, 0.f};
#pragma unroll
  for (int i = 0; i < 4; ++i)
#pragma unroll
    for (int j = 0; j < 4; ++j) acc[i][j] = z;

  const _Float16* Ap = A + (size_t)m0 * 256;
  const _Float16* Bp = Bw + (size_t)n0 * 256;
  const int gr = w * 64 + lane;        // granule handled by this lane (first half)
  const int row0 = gr >> 2, kb = gr & 3;

  for (int kt = 0; kt < 8; ++kt) {
    int k0 = kt * 32;
    gload_lds16(Ap + row0 * 256 + k0 + kb * 8, Ash + (size_t)(w * 64) * 8);
    gload_lds16(Ap + (row0 + 64) * 256 + k0 + kb * 8, Ash + (size_t)(256 + w * 64) * 8);
    gload_lds16(Bp + row0 * 256 + k0 + kb * 8, Bsh + (size_t)(w * 64) * 8);
    gload_lds16(Bp + (row0 + 64) * 256 + k0 + kb * 8, Bsh + (size_t)(256 + w * 64) * 8);
    __syncthreads();
    half8 af[4], bf[4];
#pragma unroll
    for (int im = 0; im < 4; ++im) {
      af[im] = *(const half8*)(Ash + (wm * 64 + im * 16 + ml) * 32 + qd * 8);
      bf[im] = *(const half8*)(Bsh + (wn * 64 + im * 16 + ml) * 32 + qd * 8);
    }
#pragma unroll
    for (int im = 0; im < 4; ++im)
#pragma unroll
      for (int in = 0; in < 4; ++in)
        acc[im][in] = __builtin_amdgcn_mfma_f32_16x16x32_f16(af[im], bf[in], acc[im][in], 0, 0, 0);
    __syncthreads();
  }

  // epilogue: C/D layout col=lane&15, row=quad*4+r
#pragma unroll
  for (int im = 0; im < 4; ++im) {
    int rowr0 = m0 + wm * 64 + im * 16 + qd * 4;
#pragma unroll
    for (int in = 0; in < 4; ++in) {
      int col = n0 + wn * 64 + in * 16 + ml;
      int s = col >> 8, h = (col >> 5) & 7, j = col & 31;
      _Float16* dst = s ? ko : qo;
#pragma unroll
      for (int r = 0; r < 4; ++r) {
        int rowr = rowr0 + r;
        int b = rowr >> 13, n = rowr & 8191;
        int t = n >> 10, yx = n & 1023;
        int p = b * 64 + h * 8 + t;
        dst[((size_t)p * 1024 + yx) * 32 + j] = (_Float16)acc[im][in][r];
      }
    }
  }
}

// ---- correlation + normalize + (corr @ w_corr^T + b_corr) fused ----
// grid: 512 volumes * 4 tiles of 16x16; block 256; LDS exactly 40960B -> 4 blocks/CU
__global__ __launch_bounds__(256, 4)
void corr_kernel(const _Float16* __restrict__ q16, const _Float16* __restrict__ k16,
                 const float* __restrict__ wcorr, const float* __restrict__ bcorr,
                 _Float16* __restrict__ outp) {
  __shared__ uint4 smem[2304];  // k-tile (1936 granules) then reused as corr matrix [256][72] halfs
  __shared__ uint4 wcs[256];    // w_corr fp16 [32][64]: 49 taps + bias at k=49 + zero pad

  const int tid = threadIdx.x;
  const int bx = blockIdx.x;
  const int p = bx >> 2, tile = bx & 3;
  const int y0 = (tile >> 1) * 16, x0 = (tile & 1) * 16;
  const int b = p >> 6, h = (p >> 3) & 7, t = p & 7;
  const int pk = (t < 7) ? p + 1 : p;
  const int ty = tid >> 4, tx = tid & 15;

  // stage w_corr (fp16, K padded to 64 with bias folded in at k=49)
  _Float16* wch = (_Float16*)wcs;
  for (int idx = tid; idx < 2048; idx += 256) {
    int d = idx >> 6, kk = idx & 63;
    float v = (kk < 49) ? wcorr[d * 49 + kk] : (kk == 49 ? bcorr[d] : 0.f);
    wch[idx] = (_Float16)v;
  }

  // stage k tile 22x22 vectors of 32 halfs (4 granules each), swizzled
  const _Float16* kbase = k16 + (size_t)pk * 32768;
#pragma unroll
  for (int i = 0; i < 8; ++i) {
    int g = tid + i * 256;
    if (g < 1936) {
      int vec = g >> 2, part = g & 3;
      int ky = vec / 22, kx = vec - ky * 22;
      int gy = y0 + ky - 3, gx = x0 + kx - 3;
      uint4 val = make_uint4(0u, 0u, 0u, 0u);
      if (gy >= 0 && gy < 32 && gx >= 0 && gx < 32)
        val = *(const uint4*)(kbase + ((size_t)gy * 32 + gx) * 32 + part * 8);
      int slot = (vec << 2) | (part ^ (vec & 3) ^ ((vec >> 2) & 3));
      smem[slot] = val;
    }
  }
  __syncthreads();

  // normalize k vectors in LDS
  for (int v = tid; v < 484; v += 256) {
    int base = v << 2;
    int sw = (v & 3) ^ ((v >> 2) & 3);
    uint4 gg[4];
#pragma unroll
    for (int pq = 0; pq < 4; ++pq) gg[pq] = smem[base | (pq ^ sw)];
    float ss = 0.f;
#pragma unroll
    for (int pq = 0; pq < 4; ++pq) {
      const unsigned* u = (const unsigned*)&gg[pq];
#pragma unroll
      for (int e = 0; e < 4; ++e) ss = dot2acc(u[e], u[e], ss);
    }
    float sc = 1.f / fmaxf(sqrtf(ss), 1e-12f);
#pragma unroll
    for (int pq = 0; pq < 4; ++pq) {
      unsigned* u = (unsigned*)&gg[pq];
#pragma unroll
      for (int e = 0; e < 4; ++e) u[e] = hscale(u[e], sc);
      smem[base | (pq ^ sw)] = gg[pq];
    }
  }
  __syncthreads();

  // per-thread q vector: load, normalize in-register (fp16)
  const _Float16* qptr = q16 + (size_t)p * 32768 + ((size_t)(y0 + ty) * 32 + (x0 + tx)) * 32;
  uint4 qv[4];
#pragma unroll
  for (int i = 0; i < 4; ++i) qv[i] = *(const uint4*)(qptr + i * 8);
  unsigned* qu = (unsigned*)qv;
  float qss = 0.f;
#pragma unroll
  for (int e = 0; e < 16; ++e) qss = dot2acc(qu[e], qu[e], qss);
  float qsc = 1.f / fmaxf(sqrtf(qss), 1e-12f);
#pragma unroll
  for (int e = 0; e < 16; ++e) qu[e] = hscale(qu[e], qsc);

  // 49 correlations via v_dot2_f32_f16
  float corr[49];
#pragma unroll
  for (int dy = 0; dy < 7; ++dy) {
#pragma unroll
    for (int dx = 0; dx < 7; ++dx) {
      int vec = (ty + dy) * 22 + (tx + dx);
      int base = vec << 2;
      int sw = (vec & 3) ^ ((vec >> 2) & 3);
      float c = 0.f;
#pragma unroll
      for (int pq = 0; pq < 4; ++pq) {
        uint4 kk = smem[base | (pq ^ sw)];
        const unsigned* ku = (const unsigned*)&kk;
#pragma unroll
        for (int e = 0; e < 4; ++e) c = dot2acc(qu[pq * 4 + e], ku[e], c);
      }
      corr[dy * 7 + dx] = c;
    }
  }
  __syncthreads();  // all k-tile reads done; smem reused as corr matrix

  // write corr row (pos = tid) as fp16: 49 taps, 1.0 at k=49 (bias), zeros to 63.
  // row stride 72 halfs (9 granules); granule 8 of each row left unwritten.
#pragma unroll
  for (int i = 0; i < 8; ++i) {
    uint4 val;
    unsigned* vu = (unsigned*)&val;
#pragma unroll
    for (int e = 0; e < 4; ++e) {
      int idx = i * 8 + e * 2;
      half2v hh;
      hh[0] = (_Float16)(idx < 49 ? corr[idx] : (idx == 49 ? 1.f : 0.f));
      hh[1] = (_Float16)(idx + 1 < 49 ? corr[idx + 1] : (idx + 1 == 49 ? 1.f : 0.f));
      vu[e] = __builtin_bit_cast(unsigned, hh);
    }
    smem[tid * 9 + i] = val;
  }
  __syncthreads();

  // MFMA: (256 pos x 64k) @ (64k x 32d): wave w handles m-tiles 4w..4w+3, 2 n-tiles
  _Float16* corrm = (_Float16*)smem;
  const int lane = tid & 63, w = tid >> 6;
  const int ml = lane & 15, qd = lane >> 4;
  float4v vacc[4][2];
  float4v z = {0.f, 0.f, 0.f, 0.f};
#pragma unroll
  for (int im = 0; im < 4; ++im) { vacc[im][0] = z; vacc[im][1] = z; }
#pragma unroll
  for (int ks = 0; ks < 2; ++ks) {
    half8 bfrag[2];
#pragma unroll
    for (int nt = 0; nt < 2; ++nt)
      bfrag[nt] = *(const half8*)(wch + (nt * 16 + ml) * 64 + ks * 32 + qd * 8);
#pragma unroll
    for (int im = 0; im < 4; ++im) {
      half8 afrag = *(const half8*)(corrm + (w * 64 + im * 16 + ml) * 72 + ks * 32 + qd * 8);
#pragma unroll
      for (int nt = 0; nt < 2; ++nt)
        vacc[im][nt] = __builtin_amdgcn_mfma_f32_16x16x32_f16(afrag, bfrag[nt], vacc[im][nt], 0, 0, 0);
    }
  }

  // epilogue: v -> outpre[b, n, h*32+d] fp16 (bias already folded via K=49 column)
#pragma unroll
  for (int im = 0; im < 4; ++im) {
#pragma unroll
    for (int nt = 0; nt < 2; ++nt) {
      int d = nt * 16 + ml;
#pragma unroll
      for (int r = 0; r < 4; ++r) {
        int pos = w * 64 + im * 16 + qd * 4 + r;
        int py = pos >> 4, px = pos & 15;
        int n = t * 1024 + (y0 + py) * 32 + (x0 + px);
        outp[(((size_t)b * 8192 + n) << 8) + h * 32 + d] = (_Float16)vacc[im][nt][r];
      }
    }
  }
}

// ---- proj GEMM: out = op16 @ wproj16^T + b_proj (fp32 out) ----
__global__ __launch_bounds__(256, 2)
void gemm_proj(const _Float16* __restrict__ A, const _Float16* __restrict__ Bw,
               const float* __restrict__ bp, float* __restrict__ out) {
  __shared__ _Float16 Ash[4096];
  __shared__ _Float16 Bsh[4096];
  const int tid = threadIdx.x;
  const int lane = tid & 63, w = tid >> 6;
  const int wm = w >> 1, wn = w & 1;
  const int ml = lane & 15, qd = lane >> 4;
  const int m0 = blockIdx.y * 128, n0 = blockIdx.x * 128;

  float4v acc[4][4];
  float4v z = {0.f, 0.f, 0.f, 0.f};
#pragma unroll
  for (int i = 0; i < 4; ++i)
#pragma unroll
    for (int j = 0; j < 4; ++j) acc[i][j] = z;

  const _Float16* Ap = A + (size_t)m0 * 256;
  const _Float16* Bp = Bw + (size_t)n0 * 256;
  const int gr = w * 64 + lane;
  const int row0 = gr >> 2, kb = gr & 3;

  for (int kt = 0; kt < 8; ++kt) {
    int k0 = kt * 32;
    gload_lds16(Ap + row0 * 256 + k0 + kb * 8, Ash + (size_t)(w * 64) * 8);
    gload_lds16(Ap + (row0 + 64) * 256 + k0 + kb * 8, Ash + (size_t)(256 + w * 64) * 8);
    gload_lds16(Bp + row0 * 256 + k0 + kb * 8, Bsh + (size_t)(w * 64) * 8);
    gload_lds16(Bp + (row0 + 64) * 256 + k0 + kb * 8, Bsh + (size_t)(256 + w * 64) * 8);
    __syncthreads();
    half8 af[4], bf[4];
#pragma unroll
    for (int im = 0; im < 4; ++im) {
      af[im] = *(const half8*)(Ash + (wm * 64 + im * 16 + ml) * 32 + qd * 8);
      bf[im] = *(const half8*)(Bsh + (wn * 64 + im * 16 + ml) * 32 + qd * 8);
    }
#pragma unroll
    for (int im = 0; im < 4; ++im)
#pragma unroll
      for (int in = 0; in < 4; ++in)
        acc[im][in] = __builtin_amdgcn_mfma_f32_16x16x32_f16(af[im], bf[in], acc[im][in], 0, 0, 0);
    __syncthreads();
  }

#pragma unroll
  for (int im = 0; im < 4; ++im) {
    int rowr0 = m0 + wm * 64 + im * 16 + qd * 4;
#pragma unroll
    for (int in = 0; in < 4; ++in) {
      int col = n0 + wn * 64 + in * 16 + ml;
      float bias = bp[col];
#pragma unroll
      for (int r = 0; r < 4; ++r)
        out[(size_t)(rowr0 + r) * 256 + col] = acc[im][in][r] + bias;
    }
  }
}

extern "C" void kernel_launch(void* const* d_in, const int* in_sizes, int n_in,
                              void* d_out, int out_size, void* d_ws, size_t ws_size,
                              hipStream_t stream) {
  const float* x      = (const float*)d_in[0];
  const float* w_qk   = (const float*)d_in[1];
  const float* w_corr = (const float*)d_in[2];
  const float* b_corr = (const float*)d_in[3];
  const float* w_proj = (const float*)d_in[4];
  const float* b_proj = (const float*)d_in[5];
  float* out = (float*)d_out;

  char* ws = (char*)d_ws;
  _Float16* x16   = (_Float16*)(ws);
  _Float16* q16   = (_Float16*)(ws + 33554432);
  _Float16* k16   = (_Float16*)(ws + 67108864);
  _Float16* op16  = (_Float16*)(ws + 100663296);
  _Float16* wqk16 = (_Float16*)(ws + 134217728);
  _Float16* wpj16 = (_Float16*)(ws + 134479872);

  cvt_all<<<16576, 256, 0, stream>>>((const float4*)x, (const float4*)w_qk, (const float4*)w_proj,
                                     (ushort4*)x16, (ushort4*)wqk16, (ushort4*)wpj16);
  gemm_qk<<<dim3(4, 512), 256, 0, stream>>>(x16, wqk16, q16, k16);
  corr_kernel<<<2048, 256, 0, stream>>>(q16, k16, w_corr, b_corr, op16);
  gemm_proj<<<dim3(2, 512), 256, 0, stream>>>(op16, wpj16, b_proj, out);
}